// Round 10
// baseline (317.261 us; speedup 1.0000x reference)
//
#include <hip/hip_runtime.h>
#include <cstdint>

// SelfAttention B=4 N=2048 H=16 Dh=64.
// fp32 inputs (detected; bf16 fallback) -> fp16 internal, fp32 out.
// attn: S^T in regs (mfma(A=K,B=Q)), P stays in registers -> PV via 16x16x16.
// Q pre-scaled by 0.125*log2e so softmax = bare v_exp_f32. V layout carries
// key^=4 (d&8) XOR so b64 V reads are bank-conflict-free. K/V double-buffered
// with prefetch. All epilogues store coalesced 128B rows via LDS.

typedef unsigned short ushort_t;
typedef _Float16 half_t;
typedef half_t half8 __attribute__((ext_vector_type(8)));
typedef half_t half4 __attribute__((ext_vector_type(4)));
typedef __fp16 fp16x2 __attribute__((ext_vector_type(2)));
typedef float floatx4 __attribute__((ext_vector_type(4)));

#define QSCALE 0.18033688011112043f  // 0.125 * log2(e)

__device__ __forceinline__ float bf2f(ushort_t h) {
  union { unsigned int u; float f; } v; v.u = ((unsigned int)h) << 16; return v.f;
}
__device__ __forceinline__ void async_copy16(const void* g, void* l) {
  __builtin_amdgcn_global_load_lds(
      reinterpret_cast<const __attribute__((address_space(1))) unsigned int*>(
          reinterpret_cast<uintptr_t>(g)),
      reinterpret_cast<__attribute__((address_space(3))) unsigned int*>(
          reinterpret_cast<uintptr_t>(l)),
      16, 0, 0);
}
__device__ __forceinline__ void lds_fence() {
  asm volatile("s_waitcnt lgkmcnt(0)" ::: "memory");
}
__device__ __forceinline__ void vm_fence() {
  asm volatile("s_waitcnt vmcnt(0)" ::: "memory");
}

// ---------------- dtype detector ----------------
__global__ __launch_bounds__(256) void detect_dtype(const ushort_t* __restrict__ x,
                                                    int* __restrict__ flag) {
  __shared__ int cnt;
  if (threadIdx.x == 0) cnt = 0;
  __syncthreads();
  int local = 0;
  for (int i = threadIdx.x; i < 8192; i += 256)
    if ((x[i] & 0x7F80u) == 0x7F80u) ++local;
  atomicAdd(&cnt, local);
  __syncthreads();
  if (threadIdx.x == 0) *flag = (cnt >= 2) ? 1 : 0;  // 1 = fp32 inputs
}

// ---------------- input conversion: raw -> fp16 ----------------
__global__ __launch_bounds__(256) void convert_to_f16(const void* __restrict__ src,
                                                      half_t* __restrict__ dst, int n,
                                                      const int* __restrict__ flag) {
  const int i0 = (blockIdx.x * 256 + threadIdx.x) * 4;
  if (i0 >= n) return;
  if (*flag) {
    const float* s = (const float*)src;
#pragma unroll
    for (int j = 0; j < 4; ++j) dst[i0 + j] = (half_t)s[i0 + j];
  } else {
    const ushort_t* s = (const ushort_t*)src;
#pragma unroll
    for (int j = 0; j < 4; ++j) dst[i0 + j] = (half_t)bf2f(s[i0 + j]);
  }
}

__global__ __launch_bounds__(256) void convert_bias(const void* __restrict__ src,
                                                    float* __restrict__ dst,
                                                    const int* __restrict__ flag) {
  const int i = blockIdx.x * 256 + threadIdx.x;
  if (i >= 1024) return;
  dst[i] = (*flag) ? ((const float*)src)[i] : bf2f(((const ushort_t*)src)[i]);
}

// ---------------- weight transpose + convert ----------------
__global__ __launch_bounds__(256) void transpose_conv(const void* __restrict__ src,
                                                      half_t* __restrict__ dst, int R, int C,
                                                      const int* __restrict__ flag) {
  __shared__ half_t tile[64][65];
  const int c0 = blockIdx.x * 64, r0 = blockIdx.y * 64;
  const int tx = threadIdx.x & 63, ty = threadIdx.x >> 6;
  if (*flag) {
    const float* s = (const float*)src;
    for (int i = ty; i < 64; i += 4) tile[i][tx] = (half_t)s[(size_t)(r0 + i) * C + (c0 + tx)];
  } else {
    const ushort_t* s = (const ushort_t*)src;
    for (int i = ty; i < 64; i += 4) tile[i][tx] = (half_t)bf2f(s[(size_t)(r0 + i) * C + (c0 + tx)]);
  }
  __syncthreads();
  for (int i = ty; i < 64; i += 4) dst[(size_t)(c0 + i) * R + (r0 + tx)] = tile[tx][i];
}

// ---------------- QKV GEMM ----------------
__global__ __launch_bounds__(256) void gemm_qkv_kernel(
    const half_t* __restrict__ X, const half_t* __restrict__ WT,
    half_t* __restrict__ Qb, half_t* __restrict__ Kb, half_t* __restrict__ VTb) {
  __shared__ half_t smem[128 * 136];  // K-loop: first 16384 halves = As|Bs
  half_t* As = smem;
  half_t* Bs = smem + 128 * 64;
  const int tid = threadIdx.x;
  const int wv = tid >> 6, lane = tid & 63;
  const int l15 = lane & 15, quad = lane >> 4;
  const int l7 = l15 & 7;
  const int wm = wv & 1, wn = wv >> 1;
  const int nb = blockIdx.x, mb = blockIdx.y;
  const int rlo = lane >> 3, ci = lane & 7;
  const int sw_klo = (ci ^ rlo) * 8;

  floatx4 acc[4][4];
  const floatx4 z = {0.f, 0.f, 0.f, 0.f};
#pragma unroll
  for (int mi = 0; mi < 4; ++mi)
#pragma unroll
    for (int ni = 0; ni < 4; ++ni) acc[mi][ni] = z;

  const half_t* Abase = X + (size_t)mb * 128 * 1024;
  const half_t* Bbase = WT + (size_t)nb * 128 * 1024;

  for (int k0 = 0; k0 < 1024; k0 += 64) {
#pragma unroll
    for (int j = 0; j < 4; ++j) {
      const int rb = (wv * 4 + j) * 8;
      async_copy16(Abase + (size_t)(rb + rlo) * 1024 + k0 + sw_klo, &As[rb * 64]);
    }
#pragma unroll
    for (int j = 0; j < 4; ++j) {
      const int rb = (wv * 4 + j) * 8;
      async_copy16(Bbase + (size_t)(rb + rlo) * 1024 + k0 + sw_klo, &Bs[rb * 64]);
    }
    __syncthreads();
#pragma unroll
    for (int ks = 0; ks < 2; ++ks) {
      half8 af[4], bfv[4];
#pragma unroll
      for (int mi = 0; mi < 4; ++mi) {
        const int rr = wm * 64 + mi * 16 + l15;
        af[mi] = *(const half8*)&As[rr * 64 + (((ks * 4 + quad) ^ l7) * 8)];
      }
#pragma unroll
      for (int ni = 0; ni < 4; ++ni) {
        const int rr = wn * 64 + ni * 16 + l15;
        bfv[ni] = *(const half8*)&Bs[rr * 64 + (((ks * 4 + quad) ^ l7) * 8)];
      }
#pragma unroll
      for (int mi = 0; mi < 4; ++mi)
#pragma unroll
        for (int ni = 0; ni < 4; ++ni)
          acc[mi][ni] = __builtin_amdgcn_mfma_f32_16x16x32_f16(af[mi], bfv[ni], acc[mi][ni], 0, 0, 0);
    }
    __syncthreads();
  }

  const int which = nb >> 3;  // 0=Q 1=K 2=V (block-uniform)
  if (which != 2) {
    // Q/K: stage tile in LDS [128 row][128 col] stride 132, then coalesced row stores.
    // Q additionally pre-scaled by QSCALE (folds softmax scale into the MFMA).
    const float sc = (which == 0) ? QSCALE : 1.0f;
#pragma unroll
    for (int mi = 0; mi < 4; ++mi)
#pragma unroll
      for (int ni = 0; ni < 4; ++ni) {
        const int col = wn * 64 + ni * 16 + l15;
#pragma unroll
        for (int r = 0; r < 4; ++r) {
          const int row = wm * 64 + mi * 16 + quad * 4 + r;
          smem[row * 132 + col] = (half_t)(acc[mi][ni][r] * sc);
        }
      }
    __syncthreads();
    half_t* dstB = (which == 0) ? Qb : Kb;
    const int hbase = (nb & 7) * 2;
    const int c2 = lane * 2;
    const int hh = hbase + (c2 >> 6);
    const int dd = c2 & 63;
#pragma unroll 4
    for (int i = 0; i < 32; ++i) {
      const int row = wv * 32 + i;
      const uint32_t val = *(const uint32_t*)&smem[row * 132 + c2];
      const int rowg = mb * 128 + row;
      const int bb = rowg >> 11, nn = rowg & 2047;
      *(uint32_t*)&dstB[(((size_t)(bb * 16 + hh)) * 2048 + nn) * 64 + dd] = val;
    }
  } else {
    // V: transpose through LDS (stride 136), store VT coalesced with key^=4 (d&8) XOR
    // baked in so attn's b64 V reads are bank-conflict-free.
    const int nb2 = nb - 16;
#pragma unroll
    for (int mi = 0; mi < 4; ++mi)
#pragma unroll
      for (int ni = 0; ni < 4; ++ni) {
        const int nl = wn * 64 + ni * 16 + l15;
#pragma unroll
        for (int r = 0; r < 4; ++r) {
          const int ml = wm * 64 + mi * 16 + quad * 4 + r;
          smem[nl * 136 + ml] = (half_t)acc[mi][ni][r];
        }
      }
    __syncthreads();
    const int bb = mb >> 4;
    const int nn0 = (mb * 128) & 2047;
    const int lane2 = lane * 2;
#pragma unroll 4
    for (int it = 0; it < 32; ++it) {
      const int row = it * 4 + wv;  // d-col of tile, 0..127
      const int hh = nb2 * 2 + (row >> 6);
      const int dd = row & 63;
      const int keyoff = lane2 ^ ((dd & 8) ? 4 : 0);
      const uint32_t val = *(const uint32_t*)&smem[row * 136 + lane2];
      *(uint32_t*)&VTb[((size_t)((bb * 16 + hh) * 64 + dd)) * 2048 + nn0 + keyoff] = val;
    }
  }
}

// ---------------- flash attention: dbuf K/V, S^T in regs, bare v_exp softmax ----------------
__global__ __launch_bounds__(256) void attn_kernel(
    const half_t* __restrict__ Qb, const half_t* __restrict__ Kb,
    const half_t* __restrict__ VTb, half_t* __restrict__ Ob) {
  __shared__ half_t smem[16384];  // 32 KB: K0|K1|V0|V1 (4096 halves each)
  const int tid = threadIdx.x, wv = tid >> 6, lane = tid & 63;
  const int l15 = lane & 15, quad = lane >> 4;
  const int l7 = l15 & 7;
  const int bid = blockIdx.x;
  const int xcd = bid & 7, idx = bid >> 3;
  const int bh = ((idx & 7) << 3) + xcd;  // 0..63, 16 q-tiles of one bh share an XCD
  const int qt = idx >> 3;                // 0..15
  const int bq = bh >> 4, hh = bh & 15;
  const half_t* Qg = Qb + (size_t)bh * 2048 * 64;
  const half_t* Kg = Kb + (size_t)bh * 2048 * 64;
  const half_t* Vg = VTb + (size_t)bh * 64 * 2048;
  const int q0 = qt * 128;
  const int rlo = lane >> 3, ci = lane & 7;
  const int sw_klo = (ci ^ rlo) * 8;

  // t-invariant LDS read offsets (halves)
  const int q1 = quad >> 1, qb0 = quad & 1, b3 = (l15 >> 3) & 1;
  int kx[2], vx[4];
#pragma unroll
  for (int ks = 0; ks < 2; ++ks) kx[ks] = ((ks * 4 + quad) ^ l7) * 8;
#pragma unroll
  for (int ki = 0; ki < 4; ++ki)
    vx[ki] = (((ki * 2 + q1) ^ l7) * 8) + ((qb0 ^ b3) * 4);

  // stage Q (128x64 = smem[0..8192)), pull this wave's B-operand frags
#pragma unroll
  for (int j = 0; j < 4; ++j) {
    const int rb = (wv * 4 + j) * 8;
    async_copy16(Qg + (size_t)(q0 + rb + rlo) * 64 + sw_klo, &smem[rb * 64]);
  }
  vm_fence();
  half8 aq[2][2];
#pragma unroll
  for (int ks = 0; ks < 2; ++ks)
#pragma unroll
    for (int qi = 0; qi < 2; ++qi) {
      const int rr = wv * 32 + qi * 16 + l15;
      aq[ks][qi] = *(const half8*)&smem[rr * 64 + (((ks * 4 + quad) ^ l7) * 8)];
    }
  __syncthreads();  // all waves done with Q region before K/V staging reuses it

  floatx4 o_acc[2][4];
  const floatx4 z = {0.f, 0.f, 0.f, 0.f};
  float l_st[2] = {0.f, 0.f};
#pragma unroll
  for (int qi = 0; qi < 2; ++qi)
#pragma unroll
    for (int di = 0; di < 4; ++di) o_acc[qi][di] = z;

  // stage tile 0 into buffer 0 (K at smem[0], V at smem[8192])
  {
#pragma unroll
    for (int j = 0; j < 2; ++j) {
      const int rb = (wv * 2 + j) * 8;
      async_copy16(Kg + (size_t)(rb + rlo) * 64 + sw_klo, &smem[rb * 64]);
    }
#pragma unroll
    for (int j = 0; j < 2; ++j) {
      const int db = (wv * 2 + j) * 8;
      async_copy16(Vg + (size_t)(db + rlo) * 2048 + sw_klo, &smem[8192 + db * 64]);
    }
  }

  for (int t = 0; t < 32; ++t) {
    const int co = (t & 1) * 4096;  // current buffer offset (halves)
    const int po = 4096 - co;       // prefetch buffer offset
    __syncthreads();  // vmcnt drained by compiler -> current buffers staged
    if (t < 31) {     // prefetch t+1, overlapping compute
#pragma unroll
      for (int j = 0; j < 2; ++j) {
        const int rb = (wv * 2 + j) * 8;
        async_copy16(Kg + (size_t)((t + 1) * 64 + rb + rlo) * 64 + sw_klo,
                     &smem[po + rb * 64]);
      }
#pragma unroll
      for (int j = 0; j < 2; ++j) {
        const int db = (wv * 2 + j) * 8;
        async_copy16(Vg + (size_t)(db + rlo) * 2048 + (t + 1) * 64 + sw_klo,
                     &smem[8192 + po + db * 64]);
      }
    }
    const half_t* Kc = &smem[co];
    const half_t* Vc = &smem[8192 + co];

    // S^T = mfma(A=K, B=Q'): lane=query, regs=keys. Q pre-scaled -> s = 0.125*log2e*qk.
    floatx4 s_acc[4][2];
#pragma unroll
    for (int ki = 0; ki < 4; ++ki)
#pragma unroll
      for (int qi = 0; qi < 2; ++qi) s_acc[ki][qi] = z;
#pragma unroll
    for (int ks = 0; ks < 2; ++ks) {
      half8 bk[4];
#pragma unroll
      for (int ki = 0; ki < 4; ++ki)
        bk[ki] = *(const half8*)&Kc[(ki * 16 + l15) * 64 + kx[ks]];
#pragma unroll
      for (int ki = 0; ki < 4; ++ki)
#pragma unroll
        for (int qi = 0; qi < 2; ++qi)
          s_acc[ki][qi] = __builtin_amdgcn_mfma_f32_16x16x32_f16(bk[ki], aq[ks][qi], s_acc[ki][qi], 0, 0, 0);
    }

    // softmax: p = exp2(s) (shift-free; normalization cancels), pack via pkrtz
    half4 ap[4][2];
#pragma unroll
    for (int ki = 0; ki < 4; ++ki)
#pragma unroll
      for (int qi = 0; qi < 2; ++qi) {
        const float p0 = __builtin_amdgcn_exp2f(s_acc[ki][qi][0]);
        const float p1 = __builtin_amdgcn_exp2f(s_acc[ki][qi][1]);
        const float p2 = __builtin_amdgcn_exp2f(s_acc[ki][qi][2]);
        const float p3 = __builtin_amdgcn_exp2f(s_acc[ki][qi][3]);
        l_st[qi] += (p0 + p1) + (p2 + p3);
        union { fp16x2 v; uint32_t u; } lo_, hi_;
        lo_.v = __builtin_amdgcn_cvt_pkrtz(p0, p1);
        hi_.v = __builtin_amdgcn_cvt_pkrtz(p2, p3);
        union { uint32_t u[2]; half4 h; } a_;
        a_.u[0] = lo_.u; a_.u[1] = hi_.u;
        ap[ki][qi] = a_.h;
      }

    // PV via 16x16x16: A = P regs (m=l15=q, k=quad*4+j=key), B = V^T LDS (conflict-free)
#pragma unroll
    for (int ki = 0; ki < 4; ++ki) {
      half4 bv[4];
#pragma unroll
      for (int di = 0; di < 4; ++di)
        bv[di] = *(const half4*)&Vc[(di * 16 + l15) * 64 + vx[ki]];
#pragma unroll
      for (int qi = 0; qi < 2; ++qi)
#pragma unroll
        for (int di = 0; di < 4; ++di)
          o_acc[qi][di] = __builtin_amdgcn_mfma_f32_16x16x16f16(ap[ki][qi], bv[di], o_acc[qi][di], 0, 0, 0);
    }
  }

  // l reduction (lane=query; quads hold partials)
  float linv[2];
#pragma unroll
  for (int qi = 0; qi < 2; ++qi) {
    float rs = l_st[qi];
    rs += __shfl_xor(rs, 16);
    rs += __shfl_xor(rs, 32);
    linv[qi] = 1.0f / rs;
  }

  __syncthreads();  // all waves done with K/V buffers; smem free for O staging
  // O -> LDS [row][d] stride 72, then coalesced 128B row stores
#pragma unroll
  for (int qi = 0; qi < 2; ++qi)
#pragma unroll
    for (int r = 0; r < 4; ++r) {
      const float inv = __shfl(linv[qi], quad * 4 + r);
      const int row = wv * 32 + qi * 16 + quad * 4 + r;
#pragma unroll
      for (int di = 0; di < 4; ++di)
        smem[row * 72 + di * 16 + l15] = (half_t)(o_acc[qi][di][r] * inv);
    }
  lds_fence();  // wave-local rows: order half stores before uint32 reads
  const int c2 = (lane & 31) * 2;
  const int rsel = lane >> 5;
#pragma unroll 4
  for (int i = 0; i < 16; ++i) {
    const int row = wv * 32 + i * 2 + rsel;
    const uint32_t val = *(const uint32_t*)&smem[row * 72 + c2];
    const int nn = q0 + row;
    *(uint32_t*)&Ob[((size_t)(bq * 2048 + nn)) * 1024 + hh * 64 + c2] = val;
  }
}

// ---------------- out GEMM (swizzled LDS): out = O @ w_out + b, fp32 out ----------------
__global__ __launch_bounds__(256) void gemm_out_kernel(
    const half_t* __restrict__ A, const half_t* __restrict__ WT,
    const float* __restrict__ bias, float* __restrict__ out) {
  __shared__ half_t As[128 * 64];
  __shared__ half_t Bs[128 * 64];
  const int tid = threadIdx.x;
  const int wv = tid >> 6, lane = tid & 63;
  const int l15 = lane & 15, quad = lane >> 4;
  const int l7 = l15 & 7;
  const int wm = wv & 1, wn = wv >> 1;
  const int nb = blockIdx.x, mb = blockIdx.y;
  const int rlo = lane >> 3, ci = lane & 7;
  const int sw_klo = (ci ^ rlo) * 8;

  floatx4 acc[4][4];
  const floatx4 z = {0.f, 0.f, 0.f, 0.f};
#pragma unroll
  for (int mi = 0; mi < 4; ++mi)
#pragma unroll
    for (int ni = 0; ni < 4; ++ni) acc[mi][ni] = z;

  const half_t* Abase = A + (size_t)mb * 128 * 1024;
  const half_t* Bbase = WT + (size_t)nb * 128 * 1024;

  for (int k0 = 0; k0 < 1024; k0 += 64) {
#pragma unroll
    for (int j = 0; j < 4; ++j) {
      const int rb = (wv * 4 + j) * 8;
      async_copy16(Abase + (size_t)(rb + rlo) * 1024 + k0 + sw_klo, &As[rb * 64]);
    }
#pragma unroll
    for (int j = 0; j < 4; ++j) {
      const int rb = (wv * 4 + j) * 8;
      async_copy16(Bbase + (size_t)(rb + rlo) * 1024 + k0 + sw_klo, &Bs[rb * 64]);
    }
    __syncthreads();
#pragma unroll
    for (int ks = 0; ks < 2; ++ks) {
      half8 af[4], bfv[4];
#pragma unroll
      for (int mi = 0; mi < 4; ++mi) {
        const int rr = wm * 64 + mi * 16 + l15;
        af[mi] = *(const half8*)&As[rr * 64 + (((ks * 4 + quad) ^ l7) * 8)];
      }
#pragma unroll
      for (int ni = 0; ni < 4; ++ni) {
        const int rr = wn * 64 + ni * 16 + l15;
        bfv[ni] = *(const half8*)&Bs[rr * 64 + (((ks * 4 + quad) ^ l7) * 8)];
      }
#pragma unroll
      for (int mi = 0; mi < 4; ++mi)
#pragma unroll
        for (int ni = 0; ni < 4; ++ni)
          acc[mi][ni] = __builtin_amdgcn_mfma_f32_16x16x32_f16(af[mi], bfv[ni], acc[mi][ni], 0, 0, 0);
    }
    __syncthreads();
  }

#pragma unroll
  for (int mi = 0; mi < 4; ++mi) {
#pragma unroll
    for (int ni = 0; ni < 4; ++ni) {
      const int colg = nb * 128 + wn * 64 + ni * 16 + l15;
      const float bs = bias[colg];
#pragma unroll
      for (int r = 0; r < 4; ++r) {
        const int rowg = mb * 128 + wm * 64 + mi * 16 + quad * 4 + r;
        out[(size_t)rowg * 1024 + colg] = acc[mi][ni][r] + bs;
      }
    }
  }
}

extern "C" void kernel_launch(void* const* d_in, const int* in_sizes, int n_in,
                              void* d_out, int out_size, void* d_ws, size_t ws_size,
                              hipStream_t stream) {
  const void* x_raw     = d_in[0];
  const void* w_qkv_raw = d_in[1];
  const void* w_out_raw = d_in[2];
  const void* b_out_raw = d_in[3];
  float* out = (float*)d_out;

  char* ws = (char*)d_ws;
  half_t* xb    = (half_t*)(ws);                      // 16 MB (reused as Ob)
  half_t* Qb    = (half_t*)(ws + ((size_t)16 << 20)); // 16 MB
  half_t* Kb    = (half_t*)(ws + ((size_t)32 << 20)); // 16 MB
  half_t* VTb   = (half_t*)(ws + ((size_t)48 << 20)); // 16 MB
  half_t* WTqkv = (half_t*)(ws + ((size_t)64 << 20)); //  6 MB
  half_t* WTout = (half_t*)(ws + ((size_t)70 << 20)); //  2 MB
  float*  bb    = (float*)(ws + ((size_t)72 << 20));  //  4 KB
  int*    flag  = (int*)(ws + ((size_t)72 << 20) + 8192);
  half_t* Ob    = xb;  // xb dead after gemm_qkv

  detect_dtype<<<1, 256, 0, stream>>>((const ushort_t*)x_raw, flag);
  convert_to_f16<<<8192, 256, 0, stream>>>(x_raw, xb, 8192 * 1024, flag);
  convert_bias<<<4, 256, 0, stream>>>(b_out_raw, bb, flag);
  transpose_conv<<<dim3(48, 16), 256, 0, stream>>>(w_qkv_raw, WTqkv, 1024, 3072, flag);
  transpose_conv<<<dim3(16, 16), 256, 0, stream>>>(w_out_raw, WTout, 1024, 1024, flag);
  gemm_qkv_kernel<<<dim3(24, 64), 256, 0, stream>>>(xb, WTqkv, Qb, Kb, VTb);
  attn_kernel<<<1024, 256, 0, stream>>>(Qb, Kb, VTb, Ob);
  gemm_out_kernel<<<dim3(8, 64), 256, 0, stream>>>(Ob, WTout, bb, out);
}

// Round 11
// 299.089 us; speedup vs baseline: 1.0608x; 1.0608x over previous
//
#include <hip/hip_runtime.h>
#include <cstdint>

// SelfAttention B=4 N=2048 H=16 Dh=64.
// fp32 inputs (detected; bf16 fallback) -> fp16 internal, fp32 out.
// attn: S^T in regs (mfma(A=K,B=Q)), P stays in registers -> PV via 16x16x16.
// Q pre-scaled by 0.125*log2e so softmax = bare v_exp_f32. V layout carries
// key^=4 (d&8) XOR so b64 V reads are bank-conflict-free. K/V double-buffered.
// GEMM grids are XCD-swizzled: each XCD owns an 8-row mb stripe (A in L2).

typedef unsigned short ushort_t;
typedef _Float16 half_t;
typedef half_t half8 __attribute__((ext_vector_type(8)));
typedef half_t half4 __attribute__((ext_vector_type(4)));
typedef __fp16 fp16x2 __attribute__((ext_vector_type(2)));
typedef float floatx4 __attribute__((ext_vector_type(4)));

#define QSCALE 0.18033688011112043f  // 0.125 * log2(e)

__device__ __forceinline__ float bf2f(ushort_t h) {
  union { unsigned int u; float f; } v; v.u = ((unsigned int)h) << 16; return v.f;
}
__device__ __forceinline__ void async_copy16(const void* g, void* l) {
  __builtin_amdgcn_global_load_lds(
      reinterpret_cast<const __attribute__((address_space(1))) unsigned int*>(
          reinterpret_cast<uintptr_t>(g)),
      reinterpret_cast<__attribute__((address_space(3))) unsigned int*>(
          reinterpret_cast<uintptr_t>(l)),
      16, 0, 0);
}
__device__ __forceinline__ void lds_fence() {
  asm volatile("s_waitcnt lgkmcnt(0)" ::: "memory");
}
__device__ __forceinline__ void vm_fence() {
  asm volatile("s_waitcnt vmcnt(0)" ::: "memory");
}

// ---------------- dtype detector ----------------
__global__ __launch_bounds__(256) void detect_dtype(const ushort_t* __restrict__ x,
                                                    int* __restrict__ flag) {
  __shared__ int cnt;
  if (threadIdx.x == 0) cnt = 0;
  __syncthreads();
  int local = 0;
  for (int i = threadIdx.x; i < 8192; i += 256)
    if ((x[i] & 0x7F80u) == 0x7F80u) ++local;
  atomicAdd(&cnt, local);
  __syncthreads();
  if (threadIdx.x == 0) *flag = (cnt >= 2) ? 1 : 0;  // 1 = fp32 inputs
}

// ---------------- input conversion: raw -> fp16 ----------------
__global__ __launch_bounds__(256) void convert_to_f16(const void* __restrict__ src,
                                                      half_t* __restrict__ dst, int n,
                                                      const int* __restrict__ flag) {
  const int i0 = (blockIdx.x * 256 + threadIdx.x) * 4;
  if (i0 >= n) return;
  if (*flag) {
    const float* s = (const float*)src;
#pragma unroll
    for (int j = 0; j < 4; ++j) dst[i0 + j] = (half_t)s[i0 + j];
  } else {
    const ushort_t* s = (const ushort_t*)src;
#pragma unroll
    for (int j = 0; j < 4; ++j) dst[i0 + j] = (half_t)bf2f(s[i0 + j]);
  }
}

__global__ __launch_bounds__(256) void convert_bias(const void* __restrict__ src,
                                                    float* __restrict__ dst,
                                                    const int* __restrict__ flag) {
  const int i = blockIdx.x * 256 + threadIdx.x;
  if (i >= 1024) return;
  dst[i] = (*flag) ? ((const float*)src)[i] : bf2f(((const ushort_t*)src)[i]);
}

// ---------------- weight transpose + convert (both weights in one launch) ----------------
__global__ __launch_bounds__(256) void transpose_conv2(const void* __restrict__ srcA,
                                                       half_t* __restrict__ dstA,
                                                       const void* __restrict__ srcB,
                                                       half_t* __restrict__ dstB,
                                                       const int* __restrict__ flag) {
  __shared__ half_t tile[64][65];
  const int bx = blockIdx.x;
  const void* src; half_t* dst; int C, c0;
  if (bx < 48) { src = srcA; dst = dstA; C = 3072; c0 = bx * 64; }
  else         { src = srcB; dst = dstB; C = 1024; c0 = (bx - 48) * 64; }
  const int R = 1024;
  const int r0 = blockIdx.y * 64;
  const int tx = threadIdx.x & 63, ty = threadIdx.x >> 6;
  if (*flag) {
    const float* s = (const float*)src;
    for (int i = ty; i < 64; i += 4) tile[i][tx] = (half_t)s[(size_t)(r0 + i) * C + (c0 + tx)];
  } else {
    const ushort_t* s = (const ushort_t*)src;
    for (int i = ty; i < 64; i += 4) tile[i][tx] = (half_t)bf2f(s[(size_t)(r0 + i) * C + (c0 + tx)]);
  }
  __syncthreads();
  for (int i = ty; i < 64; i += 4) dst[(size_t)(c0 + i) * R + (r0 + tx)] = tile[tx][i];
}

// ---------------- QKV GEMM (XCD-swizzled grid) ----------------
__global__ __launch_bounds__(256) void gemm_qkv_kernel(
    const half_t* __restrict__ X, const half_t* __restrict__ WT,
    half_t* __restrict__ Qb, half_t* __restrict__ Kb, half_t* __restrict__ VTb) {
  __shared__ half_t smem[128 * 136];  // K-loop: first 16384 halves = As|Bs
  half_t* As = smem;
  half_t* Bs = smem + 128 * 64;
  const int tid = threadIdx.x;
  const int wv = tid >> 6, lane = tid & 63;
  const int l15 = lane & 15, quad = lane >> 4;
  const int l7 = l15 & 7;
  const int wm = wv & 1, wn = wv >> 1;
  // XCD decode: each XCD owns mb stripe [xcd*8, xcd*8+8), iterates mb-fastest.
  const int bid = blockIdx.x;
  const int xcd = bid & 7, idx = bid >> 3;   // idx 0..191
  const int mb = xcd * 8 + (idx & 7);        // 0..63
  const int nb = idx >> 3;                   // 0..23
  const int rlo = lane >> 3, ci = lane & 7;
  const int sw_klo = (ci ^ rlo) * 8;

  floatx4 acc[4][4];
  const floatx4 z = {0.f, 0.f, 0.f, 0.f};
#pragma unroll
  for (int mi = 0; mi < 4; ++mi)
#pragma unroll
    for (int ni = 0; ni < 4; ++ni) acc[mi][ni] = z;

  const half_t* Abase = X + (size_t)mb * 128 * 1024;
  const half_t* Bbase = WT + (size_t)nb * 128 * 1024;

  for (int k0 = 0; k0 < 1024; k0 += 64) {
#pragma unroll
    for (int j = 0; j < 4; ++j) {
      const int rb = (wv * 4 + j) * 8;
      async_copy16(Abase + (size_t)(rb + rlo) * 1024 + k0 + sw_klo, &As[rb * 64]);
    }
#pragma unroll
    for (int j = 0; j < 4; ++j) {
      const int rb = (wv * 4 + j) * 8;
      async_copy16(Bbase + (size_t)(rb + rlo) * 1024 + k0 + sw_klo, &Bs[rb * 64]);
    }
    __syncthreads();
#pragma unroll
    for (int ks = 0; ks < 2; ++ks) {
      half8 af[4], bfv[4];
#pragma unroll
      for (int mi = 0; mi < 4; ++mi) {
        const int rr = wm * 64 + mi * 16 + l15;
        af[mi] = *(const half8*)&As[rr * 64 + (((ks * 4 + quad) ^ l7) * 8)];
      }
#pragma unroll
      for (int ni = 0; ni < 4; ++ni) {
        const int rr = wn * 64 + ni * 16 + l15;
        bfv[ni] = *(const half8*)&Bs[rr * 64 + (((ks * 4 + quad) ^ l7) * 8)];
      }
#pragma unroll
      for (int mi = 0; mi < 4; ++mi)
#pragma unroll
        for (int ni = 0; ni < 4; ++ni)
          acc[mi][ni] = __builtin_amdgcn_mfma_f32_16x16x32_f16(af[mi], bfv[ni], acc[mi][ni], 0, 0, 0);
    }
    __syncthreads();
  }

  const int which = nb >> 3;  // 0=Q 1=K 2=V (block-uniform)
  if (which != 2) {
    // Q/K: stage tile in LDS stride 132, then coalesced row stores.
    const float sc = (which == 0) ? QSCALE : 1.0f;
#pragma unroll
    for (int mi = 0; mi < 4; ++mi)
#pragma unroll
      for (int ni = 0; ni < 4; ++ni) {
        const int col = wn * 64 + ni * 16 + l15;
#pragma unroll
        for (int r = 0; r < 4; ++r) {
          const int row = wm * 64 + mi * 16 + quad * 4 + r;
          smem[row * 132 + col] = (half_t)(acc[mi][ni][r] * sc);
        }
      }
    __syncthreads();
    half_t* dstB = (which == 0) ? Qb : Kb;
    const int hbase = (nb & 7) * 2;
    const int c2 = lane * 2;
    const int hh = hbase + (c2 >> 6);
    const int dd = c2 & 63;
#pragma unroll 4
    for (int i = 0; i < 32; ++i) {
      const int row = wv * 32 + i;
      const uint32_t val = *(const uint32_t*)&smem[row * 132 + c2];
      const int rowg = mb * 128 + row;
      const int bb = rowg >> 11, nn = rowg & 2047;
      *(uint32_t*)&dstB[(((size_t)(bb * 16 + hh)) * 2048 + nn) * 64 + dd] = val;
    }
  } else {
    // V: transpose through LDS (stride 136), store VT coalesced with key^=4 (d&8) XOR.
    const int nb2 = nb - 16;
#pragma unroll
    for (int mi = 0; mi < 4; ++mi)
#pragma unroll
      for (int ni = 0; ni < 4; ++ni) {
        const int nl = wn * 64 + ni * 16 + l15;
#pragma unroll
        for (int r = 0; r < 4; ++r) {
          const int ml = wm * 64 + mi * 16 + quad * 4 + r;
          smem[nl * 136 + ml] = (half_t)acc[mi][ni][r];
        }
      }
    __syncthreads();
    const int bb = mb >> 4;
    const int nn0 = (mb * 128) & 2047;
    const int lane2 = lane * 2;
#pragma unroll 4
    for (int it = 0; it < 32; ++it) {
      const int row = it * 4 + wv;  // d-col of tile, 0..127
      const int hh = nb2 * 2 + (row >> 6);
      const int dd = row & 63;
      const int keyoff = lane2 ^ ((dd & 8) ? 4 : 0);
      const uint32_t val = *(const uint32_t*)&smem[row * 136 + lane2];
      *(uint32_t*)&VTb[((size_t)((bb * 16 + hh) * 64 + dd)) * 2048 + nn0 + keyoff] = val;
    }
  }
}

// ---------------- flash attention: dbuf K/V, S^T in regs, bare v_exp softmax ----------------
__global__ __launch_bounds__(256) void attn_kernel(
    const half_t* __restrict__ Qb, const half_t* __restrict__ Kb,
    const half_t* __restrict__ VTb, half_t* __restrict__ Ob) {
  __shared__ half_t smem[16384];  // 32 KB: K0|K1|V0|V1 (4096 halves each)
  const int tid = threadIdx.x, wv = tid >> 6, lane = tid & 63;
  const int l15 = lane & 15, quad = lane >> 4;
  const int l7 = l15 & 7;
  const int bid = blockIdx.x;
  const int xcd = bid & 7, idx = bid >> 3;
  const int bh = ((idx & 7) << 3) + xcd;  // 16 q-tiles of one bh share an XCD
  const int qt = idx >> 3;                // 0..15
  const int bq = bh >> 4, hh = bh & 15;
  const half_t* Qg = Qb + (size_t)bh * 2048 * 64;
  const half_t* Kg = Kb + (size_t)bh * 2048 * 64;
  const half_t* Vg = VTb + (size_t)bh * 64 * 2048;
  const int q0 = qt * 128;
  const int rlo = lane >> 3, ci = lane & 7;
  const int sw_klo = (ci ^ rlo) * 8;

  // t-invariant LDS read offsets (halves)
  const int q1 = quad >> 1, qb0 = quad & 1, b3 = (l15 >> 3) & 1;
  int kx[2], vx[4];
#pragma unroll
  for (int ks = 0; ks < 2; ++ks) kx[ks] = ((ks * 4 + quad) ^ l7) * 8;
#pragma unroll
  for (int ki = 0; ki < 4; ++ki)
    vx[ki] = (((ki * 2 + q1) ^ l7) * 8) + ((qb0 ^ b3) * 4);

  // stage Q, pull this wave's B-operand frags
#pragma unroll
  for (int j = 0; j < 4; ++j) {
    const int rb = (wv * 4 + j) * 8;
    async_copy16(Qg + (size_t)(q0 + rb + rlo) * 64 + sw_klo, &smem[rb * 64]);
  }
  vm_fence();
  half8 aq[2][2];
#pragma unroll
  for (int ks = 0; ks < 2; ++ks)
#pragma unroll
    for (int qi = 0; qi < 2; ++qi) {
      const int rr = wv * 32 + qi * 16 + l15;
      aq[ks][qi] = *(const half8*)&smem[rr * 64 + (((ks * 4 + quad) ^ l7) * 8)];
    }
  __syncthreads();  // all waves done with Q region before K/V staging reuses it

  floatx4 o_acc[2][4];
  const floatx4 z = {0.f, 0.f, 0.f, 0.f};
  float l_st[2] = {0.f, 0.f};
#pragma unroll
  for (int qi = 0; qi < 2; ++qi)
#pragma unroll
    for (int di = 0; di < 4; ++di) o_acc[qi][di] = z;

  // stage tile 0 into buffer 0 (K at smem[0], V at smem[8192])
  {
#pragma unroll
    for (int j = 0; j < 2; ++j) {
      const int rb = (wv * 2 + j) * 8;
      async_copy16(Kg + (size_t)(rb + rlo) * 64 + sw_klo, &smem[rb * 64]);
    }
#pragma unroll
    for (int j = 0; j < 2; ++j) {
      const int db = (wv * 2 + j) * 8;
      async_copy16(Vg + (size_t)(db + rlo) * 2048 + sw_klo, &smem[8192 + db * 64]);
    }
  }

  for (int t = 0; t < 32; ++t) {
    const int co = (t & 1) * 4096;
    const int po = 4096 - co;
    __syncthreads();
    if (t < 31) {  // prefetch t+1, overlapping compute
#pragma unroll
      for (int j = 0; j < 2; ++j) {
        const int rb = (wv * 2 + j) * 8;
        async_copy16(Kg + (size_t)((t + 1) * 64 + rb + rlo) * 64 + sw_klo,
                     &smem[po + rb * 64]);
      }
#pragma unroll
      for (int j = 0; j < 2; ++j) {
        const int db = (wv * 2 + j) * 8;
        async_copy16(Vg + (size_t)(db + rlo) * 2048 + (t + 1) * 64 + sw_klo,
                     &smem[8192 + po + db * 64]);
      }
    }
    const half_t* Kc = &smem[co];
    const half_t* Vc = &smem[8192 + co];

    // S^T = mfma(A=K, B=Q'): lane=query, regs=keys.
    floatx4 s_acc[4][2];
#pragma unroll
    for (int ki = 0; ki < 4; ++ki)
#pragma unroll
      for (int qi = 0; qi < 2; ++qi) s_acc[ki][qi] = z;
#pragma unroll
    for (int ks = 0; ks < 2; ++ks) {
      half8 bk[4];
#pragma unroll
      for (int ki = 0; ki < 4; ++ki)
        bk[ki] = *(const half8*)&Kc[(ki * 16 + l15) * 64 + kx[ks]];
#pragma unroll
      for (int ki = 0; ki < 4; ++ki)
#pragma unroll
        for (int qi = 0; qi < 2; ++qi)
          s_acc[ki][qi] = __builtin_amdgcn_mfma_f32_16x16x32_f16(bk[ki], aq[ks][qi], s_acc[ki][qi], 0, 0, 0);
    }

    // softmax: p = exp2(s) (shift-free), pack via pkrtz
    half4 ap[4][2];
#pragma unroll
    for (int ki = 0; ki < 4; ++ki)
#pragma unroll
      for (int qi = 0; qi < 2; ++qi) {
        const float p0 = __builtin_amdgcn_exp2f(s_acc[ki][qi][0]);
        const float p1 = __builtin_amdgcn_exp2f(s_acc[ki][qi][1]);
        const float p2 = __builtin_amdgcn_exp2f(s_acc[ki][qi][2]);
        const float p3 = __builtin_amdgcn_exp2f(s_acc[ki][qi][3]);
        l_st[qi] += (p0 + p1) + (p2 + p3);
        union { fp16x2 v; uint32_t u; } lo_, hi_;
        lo_.v = __builtin_amdgcn_cvt_pkrtz(p0, p1);
        hi_.v = __builtin_amdgcn_cvt_pkrtz(p2, p3);
        union { uint32_t u[2]; half4 h; } a_;
        a_.u[0] = lo_.u; a_.u[1] = hi_.u;
        ap[ki][qi] = a_.h;
      }

    // PV via 16x16x16: A = P regs, B = V^T LDS (conflict-free)
#pragma unroll
    for (int ki = 0; ki < 4; ++ki) {
      half4 bv[4];
#pragma unroll
      for (int di = 0; di < 4; ++di)
        bv[di] = *(const half4*)&Vc[(di * 16 + l15) * 64 + vx[ki]];
#pragma unroll
      for (int qi = 0; qi < 2; ++qi)
#pragma unroll
        for (int di = 0; di < 4; ++di)
          o_acc[qi][di] = __builtin_amdgcn_mfma_f32_16x16x16f16(ap[ki][qi], bv[di], o_acc[qi][di], 0, 0, 0);
    }
  }

  // l reduction (lane=query; quads hold partials)
  float linv[2];
#pragma unroll
  for (int qi = 0; qi < 2; ++qi) {
    float rs = l_st[qi];
    rs += __shfl_xor(rs, 16);
    rs += __shfl_xor(rs, 32);
    linv[qi] = 1.0f / rs;
  }

  __syncthreads();  // all waves done with K/V buffers; smem free for O staging
#pragma unroll
  for (int qi = 0; qi < 2; ++qi)
#pragma unroll
    for (int r = 0; r < 4; ++r) {
      const float inv = __shfl(linv[qi], quad * 4 + r);
      const int row = wv * 32 + qi * 16 + quad * 4 + r;
#pragma unroll
      for (int di = 0; di < 4; ++di)
        smem[row * 72 + di * 16 + l15] = (half_t)(o_acc[qi][di][r] * inv);
    }
  lds_fence();  // wave-local rows: order half stores before uint32 reads
  const int c2 = (lane & 31) * 2;
  const int rsel = lane >> 5;
#pragma unroll 4
  for (int i = 0; i < 16; ++i) {
    const int row = wv * 32 + i * 2 + rsel;
    const uint32_t val = *(const uint32_t*)&smem[row * 72 + c2];
    const int nn = q0 + row;
    *(uint32_t*)&Ob[((size_t)(bq * 2048 + nn)) * 1024 + hh * 64 + c2] = val;
  }
}

// ---------------- out GEMM (XCD-swizzled grid): out = O @ w_out + b, fp32 out ----------------
__global__ __launch_bounds__(256) void gemm_out_kernel(
    const half_t* __restrict__ A, const half_t* __restrict__ WT,
    const float* __restrict__ bias, float* __restrict__ out) {
  __shared__ half_t As[128 * 64];
  __shared__ half_t Bs[128 * 64];
  const int tid = threadIdx.x;
  const int wv = tid >> 6, lane = tid & 63;
  const int l15 = lane & 15, quad = lane >> 4;
  const int l7 = l15 & 7;
  const int wm = wv & 1, wn = wv >> 1;
  const int bid = blockIdx.x;
  const int xcd = bid & 7, idx = bid >> 3;   // idx 0..63
  const int mb = xcd * 8 + (idx & 7);        // 0..63
  const int nb = idx >> 3;                   // 0..7
  const int rlo = lane >> 3, ci = lane & 7;
  const int sw_klo = (ci ^ rlo) * 8;

  floatx4 acc[4][4];
  const floatx4 z = {0.f, 0.f, 0.f, 0.f};
#pragma unroll
  for (int mi = 0; mi < 4; ++mi)
#pragma unroll
    for (int ni = 0; ni < 4; ++ni) acc[mi][ni] = z;

  const half_t* Abase = A + (size_t)mb * 128 * 1024;
  const half_t* Bbase = WT + (size_t)nb * 128 * 1024;

  for (int k0 = 0; k0 < 1024; k0 += 64) {
#pragma unroll
    for (int j = 0; j < 4; ++j) {
      const int rb = (wv * 4 + j) * 8;
      async_copy16(Abase + (size_t)(rb + rlo) * 1024 + k0 + sw_klo, &As[rb * 64]);
    }
#pragma unroll
    for (int j = 0; j < 4; ++j) {
      const int rb = (wv * 4 + j) * 8;
      async_copy16(Bbase + (size_t)(rb + rlo) * 1024 + k0 + sw_klo, &Bs[rb * 64]);
    }
    __syncthreads();
#pragma unroll
    for (int ks = 0; ks < 2; ++ks) {
      half8 af[4], bfv[4];
#pragma unroll
      for (int mi = 0; mi < 4; ++mi) {
        const int rr = wm * 64 + mi * 16 + l15;
        af[mi] = *(const half8*)&As[rr * 64 + (((ks * 4 + quad) ^ l7) * 8)];
      }
#pragma unroll
      for (int ni = 0; ni < 4; ++ni) {
        const int rr = wn * 64 + ni * 16 + l15;
        bfv[ni] = *(const half8*)&Bs[rr * 64 + (((ks * 4 + quad) ^ l7) * 8)];
      }
#pragma unroll
      for (int mi = 0; mi < 4; ++mi)
#pragma unroll
        for (int ni = 0; ni < 4; ++ni)
          acc[mi][ni] = __builtin_amdgcn_mfma_f32_16x16x32_f16(af[mi], bfv[ni], acc[mi][ni], 0, 0, 0);
    }
    __syncthreads();
  }

#pragma unroll
  for (int mi = 0; mi < 4; ++mi) {
#pragma unroll
    for (int ni = 0; ni < 4; ++ni) {
      const int colg = nb * 128 + wn * 64 + ni * 16 + l15;
      const float bs = bias[colg];
#pragma unroll
      for (int r = 0; r < 4; ++r) {
        const int rowg = mb * 128 + wm * 64 + mi * 16 + quad * 4 + r;
        out[(size_t)rowg * 1024 + colg] = acc[mi][ni][r] + bs;
      }
    }
  }
}

extern "C" void kernel_launch(void* const* d_in, const int* in_sizes, int n_in,
                              void* d_out, int out_size, void* d_ws, size_t ws_size,
                              hipStream_t stream) {
  const void* x_raw     = d_in[0];
  const void* w_qkv_raw = d_in[1];
  const void* w_out_raw = d_in[2];
  const void* b_out_raw = d_in[3];
  float* out = (float*)d_out;

  char* ws = (char*)d_ws;
  half_t* xb    = (half_t*)(ws);                      // 16 MB (reused as Ob)
  half_t* Qb    = (half_t*)(ws + ((size_t)16 << 20)); // 16 MB
  half_t* Kb    = (half_t*)(ws + ((size_t)32 << 20)); // 16 MB
  half_t* VTb   = (half_t*)(ws + ((size_t)48 << 20)); // 16 MB
  half_t* WTqkv = (half_t*)(ws + ((size_t)64 << 20)); //  6 MB
  half_t* WTout = (half_t*)(ws + ((size_t)70 << 20)); //  2 MB
  float*  bb    = (float*)(ws + ((size_t)72 << 20));  //  4 KB
  int*    flag  = (int*)(ws + ((size_t)72 << 20) + 8192);
  half_t* Ob    = xb;  // xb dead after gemm_qkv

  detect_dtype<<<1, 256, 0, stream>>>((const ushort_t*)x_raw, flag);
  convert_to_f16<<<8192, 256, 0, stream>>>(x_raw, xb, 8192 * 1024, flag);
  convert_bias<<<4, 256, 0, stream>>>(b_out_raw, bb, flag);
  transpose_conv2<<<dim3(64, 16), 256, 0, stream>>>(w_qkv_raw, WTqkv, w_out_raw, WTout, flag);
  gemm_qkv_kernel<<<1536, 256, 0, stream>>>(xb, WTqkv, Qb, Kb, VTb);
  attn_kernel<<<1024, 256, 0, stream>>>(Qb, Kb, VTb, Ob);
  gemm_out_kernel<<<512, 256, 0, stream>>>(Ob, WTout, bb, out);
}